// Round 12
// baseline (1024.998 us; speedup 1.0000x reference)
//
#include <hip/hip_runtime.h>

#define Bn 64
#define Sn 512
#define Hn 1024
#define Tn 67

#define LOG2E 1.4426950408889634f
#define LN2   0.6931471805599453f

// ---------------------------------------------------------------------------
// Kernel 1: em = leaky_relu(hidden, 0.01) @ W + b  (unchanged, frozen)
// ---------------------------------------------------------------------------
__global__ __launch_bounds__(256) void gemm_em(
    const float* __restrict__ hidden, const float* __restrict__ W,
    const float* __restrict__ bias, float* __restrict__ em,
    float* __restrict__ out)
{
    __shared__ __align__(16) float hs[64][36];
    __shared__ __align__(16) float wt[80][36];

    const int tid = threadIdx.x;
    const int tx = tid & 15, ty = tid >> 4;
    const int row0 = blockIdx.x * 64;

    if (blockIdx.x == 0 && tid == 0) out[0] = 0.0f;

    float acc[4][5];
#pragma unroll
    for (int u = 0; u < 4; ++u)
#pragma unroll
        for (int v = 0; v < 5; ++v) acc[u][v] = 0.f;

    for (int kc = 0; kc < Hn; kc += 32) {
#pragma unroll
        for (int l = 0; l < 2; ++l) {
            int idx = tid + l * 256;
            int r = idx >> 3, kq = (idx & 7) << 2;
            float4 v = *reinterpret_cast<const float4*>(
                &hidden[(size_t)(row0 + r) * Hn + kc + kq]);
            v.x = v.x > 0.f ? v.x : 0.01f * v.x;
            v.y = v.y > 0.f ? v.y : 0.01f * v.y;
            v.z = v.z > 0.f ? v.z : 0.01f * v.z;
            v.w = v.w > 0.f ? v.w : 0.01f * v.w;
            *reinterpret_cast<float4*>(&hs[r][kq]) = v;
        }
        for (int idx = tid; idx < 32 * Tn; idx += 256) {
            int k = idx / Tn;
            int t = idx - k * Tn;
            wt[t][k] = W[(size_t)(kc + k) * Tn + t];
        }
        __syncthreads();

#pragma unroll
        for (int k0 = 0; k0 < 32; k0 += 4) {
            float4 hv[4], wv[5];
#pragma unroll
            for (int u = 0; u < 4; ++u)
                hv[u] = *reinterpret_cast<float4*>(&hs[ty + 16 * u][k0]);
#pragma unroll
            for (int v = 0; v < 5; ++v)
                wv[v] = *reinterpret_cast<float4*>(&wt[tx + 16 * v][k0]);
#pragma unroll
            for (int u = 0; u < 4; ++u)
#pragma unroll
                for (int v = 0; v < 5; ++v) {
                    acc[u][v] = fmaf(hv[u].x, wv[v].x, acc[u][v]);
                    acc[u][v] = fmaf(hv[u].y, wv[v].y, acc[u][v]);
                    acc[u][v] = fmaf(hv[u].z, wv[v].z, acc[u][v]);
                    acc[u][v] = fmaf(hv[u].w, wv[v].w, acc[u][v]);
                }
        }
        __syncthreads();
    }

#pragma unroll
    for (int v = 0; v < 5; ++v) {
        int c = tx + 16 * v;
        if (c < Tn) {
            float bb = bias[c];
#pragma unroll
            for (int u = 0; u < 4; ++u) {
                int row = row0 + ty + 16 * u;
                em[(size_t)row * Tn + c] = acc[u][v] + bb;
            }
        }
    }
}

// ---------------------------------------------------------------------------
// Kernel 2: barrier-free, shuffle-free scans. 64 blocks x 192 threads.
//  wave0 = CRF: dual-column dot from LDS tables, replicated-M (no shfl).
//  wave1 = Viterbi: TWO scalarized tournaments (primary col = lane, extras
//          col = 64+u2) -> no butterfly on the serial chain.
//  wave2 = numerator.
//  em staged to LDS in 16-step double-buffered chunks w/ register prefetch.
//  No __syncthreads / __shfl / __ballot inside the step loops.
// ---------------------------------------------------------------------------
#define R17(X) X(0) X(1) X(2) X(3) X(4) X(5) X(6) X(7) X(8) X(9) X(10) X(11) X(12) X(13) X(14) X(15) X(16)

__global__ __launch_bounds__(192, 1) void crf_scan8(
    const float* __restrict__ em, const int* __restrict__ labels,
    const int* __restrict__ mask, const float* __restrict__ startT,
    const float* __restrict__ endT, const float* __restrict__ trans,
    float* __restrict__ out)
{
    __shared__ __align__(16) float4 EcT4[17 * 68];  // exp(trans), col-major f4
    __shared__ __align__(16) float4 TcT4[17 * 68];  // trans, col-major f4
    __shared__ __align__(16) float emC[2][1088];    // 16 rows x 68 (CRF)
    __shared__ __align__(16) float emV[2][1088];    // (Viterbi)
    __shared__ __align__(16) float pb[2][72];
    __shared__ __align__(16) float vb[2][72];
    __shared__ int maskC[Sn];
    __shared__ int maskV[Sn];
    __shared__ unsigned char hist[Sn - 1][68];
    __shared__ int tg[Sn];
    __shared__ float numSh;
    __shared__ int lenSh;

    const int tid = threadIdx.x;
    const int wid = tid >> 6;
    const int lane = tid & 63;
    const int b = blockIdx.x;
    const float* emg = em + (size_t)b * Sn * Tn;
    const int u2 = lane < 3 ? lane : 2;
    const int st2 = 64 + u2;

    if (wid == 0) {
        // ================= CRF wave =================
#pragma unroll
        for (int i = 0; i < 8; ++i)
            maskC[lane + i * 64] = mask[b * Sn + lane + i * 64];

        for (int idx = lane; idx < 17 * 68; idx += 64) {
            int i4 = idx / 68, j = idx - i4 * 68;
            int i0 = 4 * i4;
            float4 e;
            e.x = (i0 + 0 < Tn && j < Tn) ? exp2f(trans[(i0 + 0) * Tn + j] * LOG2E) : 0.f;
            e.y = (i0 + 1 < Tn && j < Tn) ? exp2f(trans[(i0 + 1) * Tn + j] * LOG2E) : 0.f;
            e.z = (i0 + 2 < Tn && j < Tn) ? exp2f(trans[(i0 + 2) * Tn + j] * LOG2E) : 0.f;
            e.w = (i0 + 3 < Tn && j < Tn) ? exp2f(trans[(i0 + 3) * Tn + j] * LOG2E) : 0.f;
            EcT4[idx] = e;
        }
        if (lane == 0) { pb[0][67] = 0.f; pb[1][67] = 0.f; }

        // stage chunk 0 + prefetch chunk 1
        float sreg[17];
#pragma unroll
        for (int i = 0; i < 17; ++i) { int idx = lane + i * 64; if (idx > 1071) idx = 1071; sreg[i] = emg[idx]; }
#pragma unroll
        for (int i = 0; i < 17; ++i) {
            int idx = lane + i * 64;
            if (idx < 1072) { int s = idx / 67; emC[0][s * 68 + (idx - s * 67)] = sreg[i]; }
        }
#pragma unroll
        for (int i = 0; i < 17; ++i) { int idx = lane + i * 64; if (idx > 1071) idx = 1071; sreg[i] = emg[1072 + idx]; }

        float sc1 = startT[lane] + emC[0][lane];
        float sc2 = startT[st2] + emC[0][st2];
        float M = startT[0] + emC[0][0];         // uniform across lanes
        float p1 = exp2f((sc1 - M) * LOG2E);
        float p2 = exp2f((sc2 - M) * LOG2E);
        pb[0][lane] = p1;
        if (lane < 3) pb[0][64 + lane] = p2;
        float Mprev = M;

        for (int t = 1; t < Sn; ++t) {
            const int cb = (t >> 4) & 1;
            if ((t & 15) == 0) {
                const int k = t >> 4;
#pragma unroll
                for (int i = 0; i < 17; ++i) {
                    int idx = lane + i * 64;
                    if (idx < 1072) { int s = idx / 67; emC[cb][s * 68 + (idx - s * 67)] = sreg[i]; }
                }
                if (k < 31) {
                    const float* src = emg + (size_t)(k + 1) * 1072;
#pragma unroll
                    for (int i = 0; i < 17; ++i) { int idx = lane + i * 64; if (idx > 1071) idx = 1071; sreg[i] = src[idx]; }
                }
            }
            const float* row = &emC[cb][(t & 15) * 68];
            float em1 = row[lane];
            float em2 = row[st2];
            int m = maskC[t];

            const float4* P = (const float4*)&pb[(t + 1) & 1][0];
            float a0 = 0, a1 = 0, a2 = 0, a3 = 0;
            float g0 = 0, g1 = 0, g2 = 0, g3 = 0;
            float s0 = 0, s1a = 0, s2a = 0, s3a = 0;
#pragma unroll
            for (int q = 0; q < 17; ++q) {
                float4 pv = P[q];
                float4 e1 = EcT4[q * 68 + lane];
                float4 e2 = EcT4[q * 68 + 64 + u2];
                a0 = fmaf(pv.x, e1.x, a0); g0 = fmaf(pv.x, e2.x, g0);
                a1 = fmaf(pv.y, e1.y, a1); g1 = fmaf(pv.y, e2.y, g1);
                a2 = fmaf(pv.z, e1.z, a2); g2 = fmaf(pv.z, e2.z, g2);
                a3 = fmaf(pv.w, e1.w, a3); g3 = fmaf(pv.w, e2.w, g3);
                s0 += pv.x; s1a += pv.y; s2a += pv.z; s3a += pv.w;
            }
            float s1 = (a0 + a1) + (a2 + a3);
            float s2 = (g0 + g1) + (g2 + g3);
            float S = (s0 + s1a) + (s2a + s3a);
            float n1 = Mprev + log2f(s1) * LN2 + em1;
            float n2 = Mprev + log2f(s2) * LN2 + em2;
            if (m) { sc1 = n1; sc2 = n2; }
            M = Mprev + log2f(S) * LN2;          // uniform, no shfl
            p1 = exp2f((sc1 - M) * LOG2E);
            p2 = exp2f((sc2 - M) * LOG2E);
            float* Wp = &pb[t & 1][0];
            Wp[lane] = p1;
            if (lane < 3) Wp[64 + lane] = p2;
            Mprev = M;
        }

        // denominator
        float* F = &pb[0][0];
        F[lane] = sc1 + endT[lane];
        if (lane < 3) F[64 + lane] = sc2 + endT[64 + lane];
        if (lane == 0) F[67] = -1e30f;
        float mx = -1e30f;
        const float4* Fv = (const float4*)F;
#pragma unroll
        for (int q = 0; q < 17; ++q) {
            float4 v = Fv[q];
            mx = fmaxf(mx, fmaxf(fmaxf(v.x, v.y), fmaxf(v.z, v.w)));
        }
        float ss = 0.f;
#pragma unroll
        for (int q = 0; q < 17; ++q) {
            float4 v = Fv[q];
            ss += exp2f((v.x - mx) * LOG2E) + exp2f((v.y - mx) * LOG2E)
                + exp2f((v.z - mx) * LOG2E) + exp2f((v.w - mx) * LOG2E);
        }
        float denom = mx + log2f(ss) * LN2;
        __syncthreads();
        if (lane == 0) {
            int len = lenSh;
            float num = numSh + endT[labels[b * Sn + len - 1]];
            atomicAdd(out, -(num - denom) * (1.0f / (float)Bn));
        }
    } else if (wid == 1) {
        // ================= Viterbi wave =================
#pragma unroll
        for (int i = 0; i < 8; ++i)
            maskV[lane + i * 64] = mask[b * Sn + lane + i * 64];

        for (int idx = lane; idx < 17 * 68; idx += 64) {
            int i4 = idx / 68, j = idx - i4 * 68;
            int i0 = 4 * i4;
            float4 e;
            e.x = (i0 + 0 < Tn && j < Tn) ? trans[(i0 + 0) * Tn + j] : 0.f;
            e.y = (i0 + 1 < Tn && j < Tn) ? trans[(i0 + 1) * Tn + j] : 0.f;
            e.z = (i0 + 2 < Tn && j < Tn) ? trans[(i0 + 2) * Tn + j] : 0.f;
            e.w = (i0 + 3 < Tn && j < Tn) ? trans[(i0 + 3) * Tn + j] : 0.f;
            TcT4[idx] = e;
        }
        if (lane == 0) { vb[0][67] = -1e30f; vb[1][67] = -1e30f; }

        float sreg[17];
#pragma unroll
        for (int i = 0; i < 17; ++i) { int idx = lane + i * 64; if (idx > 1071) idx = 1071; sreg[i] = emg[idx]; }
#pragma unroll
        for (int i = 0; i < 17; ++i) {
            int idx = lane + i * 64;
            if (idx < 1072) { int s = idx / 67; emV[0][s * 68 + (idx - s * 67)] = sreg[i]; }
        }
#pragma unroll
        for (int i = 0; i < 17; ++i) { int idx = lane + i * 64; if (idx > 1071) idx = 1071; sreg[i] = emg[1072 + idx]; }

        float sc1 = startT[lane] + emV[0][lane];
        float sc2 = startT[st2] + emV[0][st2];
        vb[0][lane] = sc1;
        if (lane < 3) vb[0][64 + lane] = sc2;

        for (int t = 1; t < Sn; ++t) {
            const int cb = (t >> 4) & 1;
            if ((t & 15) == 0) {
                const int k = t >> 4;
#pragma unroll
                for (int i = 0; i < 17; ++i) {
                    int idx = lane + i * 64;
                    if (idx < 1072) { int s = idx / 67; emV[cb][s * 68 + (idx - s * 67)] = sreg[i]; }
                }
                if (k < 31) {
                    const float* src = emg + (size_t)(k + 1) * 1072;
#pragma unroll
                    for (int i = 0; i < 17; ++i) { int idx = lane + i * 64; if (idx > 1071) idx = 1071; sreg[i] = src[idx]; }
                }
            }
            const float* row = &emV[cb][(t & 15) * 68];
            float em1 = row[lane];
            float em2 = row[st2];
            int m = maskV[t];
            const float4* Vbc = (const float4*)&vb[(t + 1) & 1][0];

            // ---- primary tournament: target = lane ----
#define VDECL(i) float4 c##i; { float4 v = Vbc[i]; float4 tt = TcT4[i * 68 + lane]; \
            c##i.x = v.x + tt.x; c##i.y = v.y + tt.y; c##i.z = v.z + tt.z; c##i.w = v.w + tt.w; }
            R17(VDECL)
#undef VDECL
#define VQM(i) float mq##i = fmaxf(fmaxf(c##i.x, c##i.y), fmaxf(c##i.z, c##i.w));
            R17(VQM)
#undef VQM
            float m1 = fmaxf(
                fmaxf(fmaxf(fmaxf(mq0, mq1), fmaxf(mq2, mq3)),
                      fmaxf(fmaxf(mq4, mq5), fmaxf(mq6, mq7))),
                fmaxf(fmaxf(fmaxf(mq8, mq9), fmaxf(mq10, mq11)),
                      fmaxf(fmaxf(mq12, mq13), fmaxf(fmaxf(mq14, mq15), mq16))));
#define VIQ(i) int sel##i = (mq##i == m1) ? (4 * i + (c##i.x == mq##i ? 0 : (c##i.y == mq##i ? 1 : (c##i.z == mq##i ? 2 : 3)))) : 1023;
            R17(VIQ)
#undef VIQ
            int idxp = min(
                min(min(min(sel0, sel1), min(sel2, sel3)),
                    min(min(sel4, sel5), min(sel6, sel7))),
                min(min(min(sel8, sel9), min(sel10, sel11)),
                    min(min(sel12, sel13), min(min(sel14, sel15), sel16))));

            // ---- extras tournament: target = 64 + u2 (per-lane column) ----
#define WDECL(i) float4 d##i; { float4 v = Vbc[i]; float4 tt = TcT4[i * 68 + 64 + u2]; \
            d##i.x = v.x + tt.x; d##i.y = v.y + tt.y; d##i.z = v.z + tt.z; d##i.w = v.w + tt.w; }
            R17(WDECL)
#undef WDECL
#define WQM(i) float nq##i = fmaxf(fmaxf(d##i.x, d##i.y), fmaxf(d##i.z, d##i.w));
            R17(WQM)
#undef WQM
            float m2 = fmaxf(
                fmaxf(fmaxf(fmaxf(nq0, nq1), fmaxf(nq2, nq3)),
                      fmaxf(fmaxf(nq4, nq5), fmaxf(nq6, nq7))),
                fmaxf(fmaxf(fmaxf(nq8, nq9), fmaxf(nq10, nq11)),
                      fmaxf(fmaxf(nq12, nq13), fmaxf(fmaxf(nq14, nq15), nq16))));
#define WIQ(i) int tel##i = (nq##i == m2) ? (4 * i + (d##i.x == nq##i ? 0 : (d##i.y == nq##i ? 1 : (d##i.z == nq##i ? 2 : 3)))) : 1023;
            R17(WIQ)
#undef WIQ
            int idxq = min(
                min(min(min(tel0, tel1), min(tel2, tel3)),
                    min(min(tel4, tel5), min(tel6, tel7))),
                min(min(min(tel8, tel9), min(tel10, tel11)),
                    min(min(tel12, tel13), min(min(tel14, tel15), tel16))));

            float n1 = m1 + em1;
            float n2 = m2 + em2;
            int idx1 = m ? idxp : lane;
            int idx2 = m ? idxq : st2;
            if (m) { sc1 = n1; sc2 = n2; }

            hist[t - 1][lane] = (unsigned char)idx1;
            float* Wv = &vb[t & 1][0];
            Wv[lane] = sc1;
            if (lane < 3) {
                hist[t - 1][64 + lane] = (unsigned char)idx2;
                Wv[64 + lane] = sc2;
            }
        }

        // ---- final argmax (first index) over score + endT (once; shfl ok) ----
        float f1 = sc1 + endT[lane];
        float f2 = (lane < 3) ? (sc2 + endT[64 + lane]) : -1e30f;
        float zf = fmaxf(f1, f2);
#pragma unroll
        for (int k = 1; k < 64; k <<= 1) zf = fmaxf(zf, __shfl_xor(zf, k));
        unsigned long long bf1 = __ballot(f1 == zf);
        unsigned long long bf2 = __ballot((lane < 3) && (f2 == zf));
        int best = bf1 ? (__ffsll(bf1) - 1) : (64 + __ffsll(bf2) - 1);

        if (lane == 0) {
            int carry = best;
            tg[Sn - 1] = carry;
            for (int k = Sn - 2; k >= 0; --k) {
                carry = hist[k][carry];
                tg[k] = carry;
            }
        }
        float* tagsOut = out + 1 + b * Sn;
#pragma unroll
        for (int i = 0; i < 8; ++i) {
            int s = lane + i * 64;
            tagsOut[s] = maskV[s] ? (float)tg[s] : 0.f;
        }
        __syncthreads();
    } else {
        // ================= numerator wave =================
        float part = 0.f; int lenp = 0;
#pragma unroll
        for (int i = 0; i < 8; ++i) {
            int s = lane + i * 64;
            int ms = mask[b * Sn + s];
            lenp += ms;
            int ls = labels[b * Sn + s];
            if (s == 0) {
                part += startT[ls] + emg[ls];
            } else if (ms) {
                int lp = labels[b * Sn + s - 1];
                part += trans[lp * Tn + ls] + emg[(size_t)s * Tn + ls];
            }
        }
#pragma unroll
        for (int k = 1; k < 64; k <<= 1) {
            part += __shfl_xor(part, k);
            lenp += __shfl_xor(lenp, k);
        }
        if (lane == 0) { numSh = part; lenSh = lenp; }
        __syncthreads();
    }
}

extern "C" void kernel_launch(void* const* d_in, const int* in_sizes, int n_in,
                              void* d_out, int out_size, void* d_ws, size_t ws_size,
                              hipStream_t stream) {
    const float* hidden = (const float*)d_in[0];
    const int*   labels = (const int*)d_in[1];
    const int*   maskp  = (const int*)d_in[2];
    const float* W      = (const float*)d_in[3];
    const float* bias   = (const float*)d_in[4];
    const float* startT = (const float*)d_in[5];
    const float* endT   = (const float*)d_in[6];
    const float* trans  = (const float*)d_in[7];
    float* out = (float*)d_out;
    float* em  = out + 1 + (size_t)Bn * Sn;

    hipLaunchKernelGGL(gemm_em, dim3((Bn * Sn) / 64), dim3(256), 0, stream,
                       hidden, W, bias, em, out);
    hipLaunchKernelGGL(crf_scan8, dim3(Bn), dim3(192), 0, stream,
                       em, labels, maskp, startT, endT, trans, out);
}